// Round 1
// baseline (9197.372 us; speedup 1.0000x reference)
//
#include <hip/hip_runtime.h>

#define A_N   50000
#define P_N   100000
#define DIN   128
#define H_DIM 256
#define C_CLS 40
#define E_N   300000
#define EPS_LN 1e-5f

#define GF_ACC  1
#define GF_RELU 2

// ---------------- GEMM: C[N,M] = A[N,K] @ W[K,M] (+bias) (+acc) (+relu) ----------------
// 64x64 tile, TK=16, 256 threads, 4x4 per thread.
__launch_bounds__(256)
__global__ void gemm_tiled(const float* __restrict__ A, const float* __restrict__ W,
                           const float* __restrict__ bias, float* __restrict__ C,
                           int N, int K, int M, int flags)
{
    __shared__ float As[16][64];  // [k][n]
    __shared__ float Ws[16][64];  // [k][m]

    const int tx = threadIdx.x & 15;   // col group 0..15
    const int ty = threadIdx.x >> 4;   // row group 0..15
    const int n0 = blockIdx.y * 64;
    const int m0 = blockIdx.x * 64;

    float acc[4][4] = {};

    for (int k0 = 0; k0 < K; k0 += 16) {
        // --- load A tile: rows n0..n0+63, cols k0..k0+15 ---
        {
            const int r  = threadIdx.x >> 2;         // 0..63
            const int c4 = (threadIdx.x & 3) << 2;   // 0,4,8,12
            const int row = n0 + r;
            float4 v = make_float4(0.f, 0.f, 0.f, 0.f);
            if (row < N) v = *(const float4*)(A + (size_t)row * K + k0 + c4);
            As[c4 + 0][r] = v.x; As[c4 + 1][r] = v.y;
            As[c4 + 2][r] = v.z; As[c4 + 3][r] = v.w;
        }
        // --- load W tile: rows k0..k0+15, cols m0..m0+63 ---
        {
            const int kr = threadIdx.x >> 4;          // 0..15
            const int c4 = (threadIdx.x & 15) << 2;   // 0..60
            const int col = m0 + c4;
            float4 v = make_float4(0.f, 0.f, 0.f, 0.f);
            if (col < M) v = *(const float4*)(W + (size_t)(k0 + kr) * M + col);
            *(float4*)&Ws[kr][c4] = v;
        }
        __syncthreads();

        #pragma unroll
        for (int k = 0; k < 16; ++k) {
            float a[4], b[4];
            *(float4*)a = *(const float4*)&As[k][ty << 2];
            *(float4*)b = *(const float4*)&Ws[k][tx << 2];
            #pragma unroll
            for (int i = 0; i < 4; ++i)
                #pragma unroll
                for (int j = 0; j < 4; ++j)
                    acc[i][j] += a[i] * b[j];
        }
        __syncthreads();
    }

    const int colb = m0 + (tx << 2);
    if (colb >= M) return;
    float4 bv = make_float4(0.f, 0.f, 0.f, 0.f);
    if (bias) bv = *(const float4*)(bias + colb);

    #pragma unroll
    for (int i = 0; i < 4; ++i) {
        const int row = n0 + (ty << 2) + i;
        if (row >= N) break;
        float4 r;
        r.x = acc[i][0] + bv.x; r.y = acc[i][1] + bv.y;
        r.z = acc[i][2] + bv.z; r.w = acc[i][3] + bv.w;
        if (flags & GF_RELU) {
            r.x = fmaxf(r.x, 0.f); r.y = fmaxf(r.y, 0.f);
            r.z = fmaxf(r.z, 0.f); r.w = fmaxf(r.w, 0.f);
        }
        float* Cp = C + (size_t)row * M + colb;
        if (flags & GF_ACC) {
            float4 old = *(const float4*)Cp;
            r.x += old.x; r.y += old.y; r.z += old.z; r.w += old.w;
        }
        *(float4*)Cp = r;
    }
}

// ---------------- degree count ----------------
__global__ void deg_kernel(const int* __restrict__ dst, float* __restrict__ deg, int E)
{
    int i = blockIdx.x * blockDim.x + threadIdx.x;
    if (i < E) atomicAdd(&deg[dst[i]], 1.0f);
}

__global__ void rdeg_kernel(float* __restrict__ deg, int n)
{
    int i = blockIdx.x * blockDim.x + threadIdx.x;
    if (i < n) deg[i] = 1.0f / fmaxf(deg[i], 1.0f);
}

// ---------------- edge scatter-add: one wave per edge ----------------
__launch_bounds__(256)
__global__ void scatter_add_kernel(const float* __restrict__ h, const int* __restrict__ src,
                                   const int* __restrict__ dst, float* __restrict__ agg, int E)
{
    int gid = blockIdx.x * blockDim.x + threadIdx.x;
    int e = gid >> 6;
    if (e >= E) return;
    int lane = threadIdx.x & 63;
    int s = src[e], d = dst[e];
    float4 v = ((const float4*)h)[(size_t)s * (H_DIM / 4) + lane];
    float* p = agg + (size_t)d * H_DIM + (lane << 2);
    atomicAdd(p + 0, v.x); atomicAdd(p + 1, v.y);
    atomicAdd(p + 2, v.z); atomicAdd(p + 3, v.w);
}

// ---------------- per-row scale by reciprocal degree ----------------
__launch_bounds__(256)
__global__ void scale_rows_kernel(float* __restrict__ agg, const float* __restrict__ rdeg, int N)
{
    int idx = blockIdx.x * blockDim.x + threadIdx.x;  // over N * 64 float4s
    int row = idx >> 6;
    if (row >= N) return;
    float4 v = ((float4*)agg)[idx];
    float r = rdeg[row];
    v.x *= r; v.y *= r; v.z *= r; v.w *= r;
    ((float4*)agg)[idx] = v;
}

// ---------------- fused relu + residual + LayerNorm (wave per row; dst may alias prev) --------
__launch_bounds__(256)
__global__ void ln_residual_kernel(const float* __restrict__ outv, const float* __restrict__ prev,
                                   const float* __restrict__ g, const float* __restrict__ b,
                                   float* __restrict__ dst, int N)
{
    int gid = blockIdx.x * blockDim.x + threadIdx.x;
    int row = gid >> 6;
    if (row >= N) return;
    int lane = threadIdx.x & 63;
    size_t base = (size_t)row * (H_DIM / 4) + lane;
    float4 o = ((const float4*)outv)[base];
    float4 p = ((const float4*)prev)[base];
    float4 r;
    r.x = fmaxf(o.x, 0.f) + p.x;
    r.y = fmaxf(o.y, 0.f) + p.y;
    r.z = fmaxf(o.z, 0.f) + p.z;
    r.w = fmaxf(o.w, 0.f) + p.w;
    float s = r.x + r.y + r.z + r.w;
    float q = r.x * r.x + r.y * r.y + r.z * r.z + r.w * r.w;
    #pragma unroll
    for (int off = 32; off; off >>= 1) {
        s += __shfl_xor(s, off, 64);
        q += __shfl_xor(q, off, 64);
    }
    float mean = s * (1.0f / H_DIM);
    float var  = q * (1.0f / H_DIM) - mean * mean;
    float inv  = rsqrtf(var + EPS_LN);
    float4 gv = ((const float4*)g)[lane];
    float4 bv = ((const float4*)b)[lane];
    r.x = (r.x - mean) * inv * gv.x + bv.x;
    r.y = (r.y - mean) * inv * gv.y + bv.y;
    r.z = (r.z - mean) * inv * gv.z + bv.z;
    r.w = (r.w - mean) * inv * gv.w + bv.w;
    ((float4*)dst)[base] = r;
}

// ---------------- in-place log_softmax over rows of C (wave per row) ----------------
__launch_bounds__(256)
__global__ void logsoftmax_kernel(float* __restrict__ x, int N, int C)
{
    int gid = blockIdx.x * blockDim.x + threadIdx.x;
    int row = gid >> 6;
    if (row >= N) return;
    int lane = threadIdx.x & 63;
    float v = (lane < C) ? x[(size_t)row * C + lane] : -3.0e38f;
    float m = v;
    #pragma unroll
    for (int off = 32; off; off >>= 1) m = fmaxf(m, __shfl_xor(m, off, 64));
    float e = (lane < C) ? __expf(v - m) : 0.f;
    float s = e;
    #pragma unroll
    for (int off = 32; off; off >>= 1) s += __shfl_xor(s, off, 64);
    float ls = logf(s);
    if (lane < C) x[(size_t)row * C + lane] = v - m - ls;
}

// ======================================================================================
extern "C" void kernel_launch(void* const* d_in, const int* in_sizes, int n_in,
                              void* d_out, int out_size, void* d_ws, size_t ws_size,
                              hipStream_t stream)
{
    const float* x_author = (const float*)d_in[0];
    const float* x_paper  = (const float*)d_in[1];
    const int* e0s = (const int*)d_in[2]; const int* e0d = (const int*)d_in[3];
    const int* e1s = (const int*)d_in[4]; const int* e1d = (const int*)d_in[5];
    const int* e2s = (const int*)d_in[6]; const int* e2d = (const int*)d_in[7];
    const float* embWa = (const float*)d_in[8];  const float* embba = (const float*)d_in[9];
    const float* embWp = (const float*)d_in[10]; const float* embbp = (const float*)d_in[11];
    const float* Wself  = (const float*)d_in[12];
    const float* Wneigh = (const float*)d_in[13];
    const float* bconv  = (const float*)d_in[14];
    const float* lnga = (const float*)d_in[15]; const float* lnba = (const float*)d_in[16];
    const float* lngp = (const float*)d_in[17]; const float* lnbp = (const float*)d_in[18];
    const float* pW1a = (const float*)d_in[19]; const float* pb1a = (const float*)d_in[20];
    const float* pW2a = (const float*)d_in[21]; const float* pb2a = (const float*)d_in[22];
    const float* pW1p = (const float*)d_in[23]; const float* pb1p = (const float*)d_in[24];
    const float* pW2p = (const float*)d_in[25];

    // workspace layout (floats): HA | HP | OUTA | OUTP | deg0 | deg1 | deg2
    float* ws   = (float*)d_ws;
    float* HA   = ws;
    float* HP   = HA   + (size_t)A_N * H_DIM;
    float* OUTA = HP   + (size_t)P_N * H_DIM;
    float* OUTP = OUTA + (size_t)A_N * H_DIM;
    float* DEG  = OUTP + (size_t)P_N * H_DIM;
    float* deg0 = DEG;
    float* deg1 = deg0 + P_N;
    float* deg2 = deg1 + P_N;

    float* oaOut = (float*)d_out;                       // A_N * C_CLS
    float* opOut = oaOut + (size_t)A_N * C_CLS;         // P_N * H_DIM
    float* AGG   = opOut;  // reuse the op output region as aggregation scratch (P_N*H fits exactly)

    auto gemm = [&](const float* Am, const float* Wm, const float* bias, float* Cm,
                    int N, int K, int M, int flags) {
        dim3 grid((M + 63) / 64, (N + 63) / 64);
        gemm_tiled<<<grid, 256, 0, stream>>>(Am, Wm, bias, Cm, N, K, M, flags);
    };

    // ---- degrees (once; reused across layers) ----
    hipMemsetAsync(DEG, 0, (size_t)(2 * P_N + A_N) * sizeof(float), stream);
    deg_kernel<<<(E_N + 255) / 256, 256, 0, stream>>>(e0d, deg0, E_N);
    deg_kernel<<<(E_N + 255) / 256, 256, 0, stream>>>(e1d, deg1, E_N);
    deg_kernel<<<(E_N + 255) / 256, 256, 0, stream>>>(e2d, deg2, E_N);
    rdeg_kernel<<<(2 * P_N + A_N + 255) / 256, 256, 0, stream>>>(DEG, 2 * P_N + A_N);

    // ---- input embeddings ----
    gemm(x_author, embWa, embba, HA, A_N, DIN, H_DIM, 0);
    gemm(x_paper,  embWp, embbp, HP, P_N, DIN, H_DIM, 0);

    const int scatterBlocks = (E_N * 64 + 255) / 256;

    for (int l = 0; l < 2; ++l) {
        const float* Ws0 = Wself  + (size_t)(l * 3 + 0) * H_DIM * H_DIM;
        const float* Ws1 = Wself  + (size_t)(l * 3 + 1) * H_DIM * H_DIM;
        const float* Ws2 = Wself  + (size_t)(l * 3 + 2) * H_DIM * H_DIM;
        const float* Wn0 = Wneigh + (size_t)(l * 3 + 0) * H_DIM * H_DIM;
        const float* Wn1 = Wneigh + (size_t)(l * 3 + 1) * H_DIM * H_DIM;
        const float* Wn2 = Wneigh + (size_t)(l * 3 + 2) * H_DIM * H_DIM;
        const float* b0 = bconv + (size_t)(l * 3 + 0) * H_DIM;
        const float* b1 = bconv + (size_t)(l * 3 + 1) * H_DIM;
        const float* b2 = bconv + (size_t)(l * 3 + 2) * H_DIM;

        // edge type 0: author -> paper
        hipMemsetAsync(AGG, 0, (size_t)P_N * H_DIM * sizeof(float), stream);
        scatter_add_kernel<<<scatterBlocks, 256, 0, stream>>>(HA, e0s, e0d, AGG, E_N);
        scale_rows_kernel<<<(P_N * 64 + 255) / 256, 256, 0, stream>>>(AGG, deg0, P_N);
        gemm(HP,  Ws0, b0,      OUTP, P_N, H_DIM, H_DIM, 0);
        gemm(AGG, Wn0, nullptr, OUTP, P_N, H_DIM, H_DIM, GF_ACC);

        // edge type 1: paper -> paper
        hipMemsetAsync(AGG, 0, (size_t)P_N * H_DIM * sizeof(float), stream);
        scatter_add_kernel<<<scatterBlocks, 256, 0, stream>>>(HP, e1s, e1d, AGG, E_N);
        scale_rows_kernel<<<(P_N * 64 + 255) / 256, 256, 0, stream>>>(AGG, deg1, P_N);
        gemm(HP,  Ws1, b1,      OUTP, P_N, H_DIM, H_DIM, GF_ACC);
        gemm(AGG, Wn1, nullptr, OUTP, P_N, H_DIM, H_DIM, GF_ACC);

        // edge type 2: paper -> author
        hipMemsetAsync(AGG, 0, (size_t)A_N * H_DIM * sizeof(float), stream);
        scatter_add_kernel<<<scatterBlocks, 256, 0, stream>>>(HP, e2s, e2d, AGG, E_N);
        scale_rows_kernel<<<(A_N * 64 + 255) / 256, 256, 0, stream>>>(AGG, deg2, A_N);
        gemm(HA,  Ws2, b2,      OUTA, A_N, H_DIM, H_DIM, 0);
        gemm(AGG, Wn2, nullptr, OUTA, A_N, H_DIM, H_DIM, GF_ACC);

        // fused relu + residual + LN (in place into HA / HP)
        ln_residual_kernel<<<(A_N * 64 + 255) / 256, 256, 0, stream>>>(OUTA, HA, lnga, lnba, HA, A_N);
        ln_residual_kernel<<<(P_N * 64 + 255) / 256, 256, 0, stream>>>(OUTP, HP, lngp, lnbp, HP, P_N);
    }

    // ---- output heads ----
    gemm(HA, pW1a, pb1a, OUTA, A_N, H_DIM, H_DIM, GF_RELU);
    gemm(OUTA, pW2a, pb2a, oaOut, A_N, H_DIM, C_CLS, 0);
    logsoftmax_kernel<<<(A_N * 64 + 255) / 256, 256, 0, stream>>>(oaOut, A_N, C_CLS);

    gemm(HP, pW1p, pb1p, OUTP, P_N, H_DIM, H_DIM, GF_RELU);
    gemm(OUTP, pW2p, nullptr, opOut, P_N, H_DIM, H_DIM, 0);
}

// Round 2
// 3274.261 us; speedup vs baseline: 2.8090x; 2.8090x over previous
//
#include <hip/hip_runtime.h>

#define A_N   50000
#define P_N   100000
#define DIN   128
#define H_DIM 256
#define C_CLS 40
#define E_N   300000
#define EPS_LN 1e-5f

#define GF_ACC  1
#define GF_RELU 2

// ---------------- GEMM: C[N,M] = A[N,K] @ W[K,M] (+bias) (+acc) (+relu) ----------------
// 64x64 tile, TK=16, 256 threads, 4x4 per thread.
__launch_bounds__(256)
__global__ void gemm_tiled(const float* __restrict__ A, const float* __restrict__ W,
                           const float* __restrict__ bias, float* __restrict__ C,
                           int N, int K, int M, int flags)
{
    __shared__ float As[16][64];  // [k][n]
    __shared__ float Ws[16][64];  // [k][m]

    const int tx = threadIdx.x & 15;   // col group 0..15
    const int ty = threadIdx.x >> 4;   // row group 0..15
    const int n0 = blockIdx.y * 64;
    const int m0 = blockIdx.x * 64;

    float acc[4][4] = {};

    for (int k0 = 0; k0 < K; k0 += 16) {
        {
            const int r  = threadIdx.x >> 2;         // 0..63
            const int c4 = (threadIdx.x & 3) << 2;   // 0,4,8,12
            const int row = n0 + r;
            float4 v = make_float4(0.f, 0.f, 0.f, 0.f);
            if (row < N) v = *(const float4*)(A + (size_t)row * K + k0 + c4);
            As[c4 + 0][r] = v.x; As[c4 + 1][r] = v.y;
            As[c4 + 2][r] = v.z; As[c4 + 3][r] = v.w;
        }
        {
            const int kr = threadIdx.x >> 4;          // 0..15
            const int c4 = (threadIdx.x & 15) << 2;   // 0..60
            const int col = m0 + c4;
            float4 v = make_float4(0.f, 0.f, 0.f, 0.f);
            if (col < M) v = *(const float4*)(W + (size_t)(k0 + kr) * M + col);
            *(float4*)&Ws[kr][c4] = v;
        }
        __syncthreads();

        #pragma unroll
        for (int k = 0; k < 16; ++k) {
            float a[4], b[4];
            *(float4*)a = *(const float4*)&As[k][ty << 2];
            *(float4*)b = *(const float4*)&Ws[k][tx << 2];
            #pragma unroll
            for (int i = 0; i < 4; ++i)
                #pragma unroll
                for (int j = 0; j < 4; ++j)
                    acc[i][j] += a[i] * b[j];
        }
        __syncthreads();
    }

    const int colb = m0 + (tx << 2);
    if (colb >= M) return;
    float4 bv = make_float4(0.f, 0.f, 0.f, 0.f);
    if (bias) bv = *(const float4*)(bias + colb);

    #pragma unroll
    for (int i = 0; i < 4; ++i) {
        const int row = n0 + (ty << 2) + i;
        if (row >= N) break;
        float4 r;
        r.x = acc[i][0] + bv.x; r.y = acc[i][1] + bv.y;
        r.z = acc[i][2] + bv.z; r.w = acc[i][3] + bv.w;
        if (flags & GF_RELU) {
            r.x = fmaxf(r.x, 0.f); r.y = fmaxf(r.y, 0.f);
            r.z = fmaxf(r.z, 0.f); r.w = fmaxf(r.w, 0.f);
        }
        float* Cp = C + (size_t)row * M + colb;
        if (flags & GF_ACC) {
            float4 old = *(const float4*)Cp;
            r.x += old.x; r.y += old.y; r.z += old.z; r.w += old.w;
        }
        *(float4*)Cp = r;
    }
}

// ---------------- CSR build: degree count (int) ----------------
__global__ void degi_kernel(const int* __restrict__ dst, int* __restrict__ deg, int E)
{
    int i = blockIdx.x * blockDim.x + threadIdx.x;
    if (i < E) atomicAdd(&deg[dst[i]], 1);
}

// ---------------- block-wide exclusive scan helper (256 threads) ----------------
__device__ __forceinline__ int block_exscan256(int val, int* lds, int* total)
{
    int t = threadIdx.x;
    lds[t] = val;
    __syncthreads();
    #pragma unroll
    for (int off = 1; off < 256; off <<= 1) {
        int y = (t >= off) ? lds[t - off] : 0;
        __syncthreads();
        lds[t] += y;
        __syncthreads();
    }
    int inc = lds[t];
    *total = lds[255];
    __syncthreads();
    return inc - val;
}

// pass 1: each 256-thread block scans a 1024-element chunk (4/thread); writes chunk totals
__global__ void scan1_kernel(const int* __restrict__ in, int* __restrict__ out,
                             int* __restrict__ sums, int n)
{
    __shared__ int lds[256];
    int t = threadIdx.x;
    int base = blockIdx.x * 1024 + t * 4;
    int v0 = 0, v1 = 0, v2 = 0, v3 = 0;
    if (base + 3 < n) {
        int4 q = *(const int4*)(in + base);
        v0 = q.x; v1 = q.y; v2 = q.z; v3 = q.w;
    } else {
        if (base     < n) v0 = in[base];
        if (base + 1 < n) v1 = in[base + 1];
        if (base + 2 < n) v2 = in[base + 2];
    }
    int tot = v0 + v1 + v2 + v3, bt;
    int ex = block_exscan256(tot, lds, &bt);
    if (base     < n) out[base]     = ex;
    if (base + 1 < n) out[base + 1] = ex + v0;
    if (base + 2 < n) out[base + 2] = ex + v0 + v1;
    if (base + 3 < n) out[base + 3] = ex + v0 + v1 + v2;
    if (t == 0) sums[blockIdx.x] = bt;
}

// pass 2: single block scans the chunk totals (nc <= 256)
__global__ void scan2_kernel(int* __restrict__ sums, int nc)
{
    __shared__ int lds[256];
    int t = threadIdx.x;
    int v = (t < nc) ? sums[t] : 0;
    int bt;
    int ex = block_exscan256(v, lds, &bt);
    if (t < nc) sums[t] = ex;
}

// pass 3: add chunk offsets in place (result doubles as the fill cursor)
__global__ void scan3_kernel(int* __restrict__ cur, const int* __restrict__ sums, int n)
{
    int i = blockIdx.x * blockDim.x + threadIdx.x;
    if (i < n) cur[i] += sums[i >> 10];
}

// bucket fill: cursor advances; afterwards cur[d] == off[d] + deg[d]
__global__ void csr_fill_kernel(const int* __restrict__ src, const int* __restrict__ dst,
                                int* __restrict__ cur, int* __restrict__ csr, int E)
{
    int e = blockIdx.x * blockDim.x + threadIdx.x;
    if (e < E) {
        int pos = atomicAdd(&cur[dst[e]], 1);
        csr[pos] = src[e];
    }
}

// ---------------- pull-style mean aggregation: one wave per dst row ----------------
// edges of d live at [cur[d]-deg[d], cur[d])  (cursor is post-fill)
__launch_bounds__(256)
__global__ void gather_mean_kernel(const float* __restrict__ h, const int* __restrict__ cur,
                                   const int* __restrict__ deg, const int* __restrict__ csr,
                                   float* __restrict__ agg, int N)
{
    int gid = blockIdx.x * blockDim.x + threadIdx.x;
    int d = gid >> 6;
    if (d >= N) return;
    int lane = threadIdx.x & 63;
    int dg = deg[d];
    int o  = cur[d] - dg;
    float4 acc = make_float4(0.f, 0.f, 0.f, 0.f);
    for (int i = 0; i < dg; ++i) {
        int s = csr[o + i];
        float4 v = ((const float4*)h)[(size_t)s * (H_DIM / 4) + lane];
        acc.x += v.x; acc.y += v.y; acc.z += v.z; acc.w += v.w;
    }
    float r = (dg > 0) ? (1.0f / (float)dg) : 0.f;
    acc.x *= r; acc.y *= r; acc.z *= r; acc.w *= r;
    ((float4*)agg)[(size_t)d * (H_DIM / 4) + lane] = acc;
}

// ---------------- fused relu + residual + LayerNorm (wave per row; dst may alias prev) --------
__launch_bounds__(256)
__global__ void ln_residual_kernel(const float* __restrict__ outv, const float* __restrict__ prev,
                                   const float* __restrict__ g, const float* __restrict__ b,
                                   float* __restrict__ dst, int N)
{
    int gid = blockIdx.x * blockDim.x + threadIdx.x;
    int row = gid >> 6;
    if (row >= N) return;
    int lane = threadIdx.x & 63;
    size_t base = (size_t)row * (H_DIM / 4) + lane;
    float4 o = ((const float4*)outv)[base];
    float4 p = ((const float4*)prev)[base];
    float4 r;
    r.x = fmaxf(o.x, 0.f) + p.x;
    r.y = fmaxf(o.y, 0.f) + p.y;
    r.z = fmaxf(o.z, 0.f) + p.z;
    r.w = fmaxf(o.w, 0.f) + p.w;
    float s = r.x + r.y + r.z + r.w;
    float q = r.x * r.x + r.y * r.y + r.z * r.z + r.w * r.w;
    #pragma unroll
    for (int off = 32; off; off >>= 1) {
        s += __shfl_xor(s, off, 64);
        q += __shfl_xor(q, off, 64);
    }
    float mean = s * (1.0f / H_DIM);
    float var  = q * (1.0f / H_DIM) - mean * mean;
    float inv  = rsqrtf(var + EPS_LN);
    float4 gv = ((const float4*)g)[lane];
    float4 bv = ((const float4*)b)[lane];
    r.x = (r.x - mean) * inv * gv.x + bv.x;
    r.y = (r.y - mean) * inv * gv.y + bv.y;
    r.z = (r.z - mean) * inv * gv.z + bv.z;
    r.w = (r.w - mean) * inv * gv.w + bv.w;
    ((float4*)dst)[base] = r;
}

// ---------------- in-place log_softmax over rows of C (wave per row) ----------------
__launch_bounds__(256)
__global__ void logsoftmax_kernel(float* __restrict__ x, int N, int C)
{
    int gid = blockIdx.x * blockDim.x + threadIdx.x;
    int row = gid >> 6;
    if (row >= N) return;
    int lane = threadIdx.x & 63;
    float v = (lane < C) ? x[(size_t)row * C + lane] : -3.0e38f;
    float m = v;
    #pragma unroll
    for (int off = 32; off; off >>= 1) m = fmaxf(m, __shfl_xor(m, off, 64));
    float e = (lane < C) ? __expf(v - m) : 0.f;
    float s = e;
    #pragma unroll
    for (int off = 32; off; off >>= 1) s += __shfl_xor(s, off, 64);
    float ls = logf(s);
    if (lane < C) x[(size_t)row * C + lane] = v - m - ls;
}

// ======================================================================================
extern "C" void kernel_launch(void* const* d_in, const int* in_sizes, int n_in,
                              void* d_out, int out_size, void* d_ws, size_t ws_size,
                              hipStream_t stream)
{
    const float* x_author = (const float*)d_in[0];
    const float* x_paper  = (const float*)d_in[1];
    const int* e0s = (const int*)d_in[2]; const int* e0d = (const int*)d_in[3];
    const int* e1s = (const int*)d_in[4]; const int* e1d = (const int*)d_in[5];
    const int* e2s = (const int*)d_in[6]; const int* e2d = (const int*)d_in[7];
    const float* embWa = (const float*)d_in[8];  const float* embba = (const float*)d_in[9];
    const float* embWp = (const float*)d_in[10]; const float* embbp = (const float*)d_in[11];
    const float* Wself  = (const float*)d_in[12];
    const float* Wneigh = (const float*)d_in[13];
    const float* bconv  = (const float*)d_in[14];
    const float* lnga = (const float*)d_in[15]; const float* lnba = (const float*)d_in[16];
    const float* lngp = (const float*)d_in[17]; const float* lnbp = (const float*)d_in[18];
    const float* pW1a = (const float*)d_in[19]; const float* pb1a = (const float*)d_in[20];
    const float* pW2a = (const float*)d_in[21]; const float* pb2a = (const float*)d_in[22];
    const float* pW1p = (const float*)d_in[23]; const float* pb1p = (const float*)d_in[24];
    const float* pW2p = (const float*)d_in[25];

    // workspace layout: HA | HP | OUTA | OUTP | ideg | icur | icsr | isums
    float* ws   = (float*)d_ws;
    float* HA   = ws;
    float* HP   = HA   + (size_t)A_N * H_DIM;
    float* OUTA = HP   + (size_t)P_N * H_DIM;
    float* OUTP = OUTA + (size_t)A_N * H_DIM;
    int*   ideg = (int*)(OUTP + (size_t)P_N * H_DIM);
    int*   icur = ideg + (2 * P_N + A_N);
    int*   icsr = icur + (2 * P_N + A_N);
    int*   isum = icsr + 3 * E_N;            // 3 * 256 ints

    int* deg0 = ideg;          int* deg1 = deg0 + P_N;  int* deg2 = deg1 + P_N;
    int* cur0 = icur;          int* cur1 = cur0 + P_N;  int* cur2 = cur1 + P_N;
    int* csr0 = icsr;          int* csr1 = csr0 + E_N;  int* csr2 = csr1 + E_N;
    int* sum0 = isum;          int* sum1 = sum0 + 256;  int* sum2 = sum1 + 256;

    float* oaOut = (float*)d_out;                  // A_N * C_CLS
    float* opOut = oaOut + (size_t)A_N * C_CLS;    // P_N * H_DIM
    float* AGG   = opOut;  // reuse op-output region as aggregation scratch (fully overwritten later)

    auto gemm = [&](const float* Am, const float* Wm, const float* bias, float* Cm,
                    int N, int K, int M, int flags) {
        dim3 grid((M + 63) / 64, (N + 63) / 64);
        gemm_tiled<<<grid, 256, 0, stream>>>(Am, Wm, bias, Cm, N, K, M, flags);
    };

    // ---- CSR build (once; edge structure constant across layers) ----
    hipMemsetAsync(ideg, 0, (size_t)(2 * P_N + A_N) * sizeof(int), stream);
    const int eB = (E_N + 255) / 256;
    degi_kernel<<<eB, 256, 0, stream>>>(e0d, deg0, E_N);
    degi_kernel<<<eB, 256, 0, stream>>>(e1d, deg1, E_N);
    degi_kernel<<<eB, 256, 0, stream>>>(e2d, deg2, E_N);

    auto build_scan = [&](int* deg, int* cur, int* sums, int n) {
        int nc = (n + 1023) / 1024;
        scan1_kernel<<<nc, 256, 0, stream>>>(deg, cur, sums, n);
        scan2_kernel<<<1, 256, 0, stream>>>(sums, nc);
        scan3_kernel<<<(n + 255) / 256, 256, 0, stream>>>(cur, sums, n);
    };
    build_scan(deg0, cur0, sum0, P_N);
    build_scan(deg1, cur1, sum1, P_N);
    build_scan(deg2, cur2, sum2, A_N);

    csr_fill_kernel<<<eB, 256, 0, stream>>>(e0s, e0d, cur0, csr0, E_N);
    csr_fill_kernel<<<eB, 256, 0, stream>>>(e1s, e1d, cur1, csr1, E_N);
    csr_fill_kernel<<<eB, 256, 0, stream>>>(e2s, e2d, cur2, csr2, E_N);

    // ---- input embeddings ----
    gemm(x_author, embWa, embba, HA, A_N, DIN, H_DIM, 0);
    gemm(x_paper,  embWp, embbp, HP, P_N, DIN, H_DIM, 0);

    const int gBlkP = (P_N * 64 + 255) / 256;
    const int gBlkA = (A_N * 64 + 255) / 256;

    for (int l = 0; l < 2; ++l) {
        const float* Ws0 = Wself  + (size_t)(l * 3 + 0) * H_DIM * H_DIM;
        const float* Ws1 = Wself  + (size_t)(l * 3 + 1) * H_DIM * H_DIM;
        const float* Ws2 = Wself  + (size_t)(l * 3 + 2) * H_DIM * H_DIM;
        const float* Wn0 = Wneigh + (size_t)(l * 3 + 0) * H_DIM * H_DIM;
        const float* Wn1 = Wneigh + (size_t)(l * 3 + 1) * H_DIM * H_DIM;
        const float* Wn2 = Wneigh + (size_t)(l * 3 + 2) * H_DIM * H_DIM;
        const float* b0 = bconv + (size_t)(l * 3 + 0) * H_DIM;
        const float* b1 = bconv + (size_t)(l * 3 + 1) * H_DIM;
        const float* b2 = bconv + (size_t)(l * 3 + 2) * H_DIM;

        // edge type 0: author -> paper
        gather_mean_kernel<<<gBlkP, 256, 0, stream>>>(HA, cur0, deg0, csr0, AGG, P_N);
        gemm(HP,  Ws0, b0,      OUTP, P_N, H_DIM, H_DIM, 0);
        gemm(AGG, Wn0, nullptr, OUTP, P_N, H_DIM, H_DIM, GF_ACC);

        // edge type 1: paper -> paper
        gather_mean_kernel<<<gBlkP, 256, 0, stream>>>(HP, cur1, deg1, csr1, AGG, P_N);
        gemm(HP,  Ws1, b1,      OUTP, P_N, H_DIM, H_DIM, GF_ACC);
        gemm(AGG, Wn1, nullptr, OUTP, P_N, H_DIM, H_DIM, GF_ACC);

        // edge type 2: paper -> author
        gather_mean_kernel<<<gBlkA, 256, 0, stream>>>(HP, cur2, deg2, csr2, AGG, A_N);
        gemm(HA,  Ws2, b2,      OUTA, A_N, H_DIM, H_DIM, 0);
        gemm(AGG, Wn2, nullptr, OUTA, A_N, H_DIM, H_DIM, GF_ACC);

        // fused relu + residual + LN (in place into HA / HP)
        ln_residual_kernel<<<gBlkA, 256, 0, stream>>>(OUTA, HA, lnga, lnba, HA, A_N);
        ln_residual_kernel<<<gBlkP, 256, 0, stream>>>(OUTP, HP, lngp, lnbp, HP, P_N);
    }

    // ---- output heads ----
    gemm(HA, pW1a, pb1a, OUTA, A_N, H_DIM, H_DIM, GF_RELU);
    gemm(OUTA, pW2a, pb2a, oaOut, A_N, H_DIM, C_CLS, 0);
    logsoftmax_kernel<<<gBlkA, 256, 0, stream>>>(oaOut, A_N, C_CLS);

    gemm(HP, pW1p, pb1p, OUTP, P_N, H_DIM, H_DIM, GF_RELU);
    gemm(OUTP, pW2p, nullptr, opOut, P_N, H_DIM, H_DIM, 0);
}

// Round 3
// 1465.957 us; speedup vs baseline: 6.2740x; 2.2335x over previous
//
#include <hip/hip_runtime.h>

#define A_N   50000
#define P_N   100000
#define DIN   128
#define H_DIM 256
#define C_CLS 40
#define E_N   300000
#define EPS_LN 1e-5f

typedef short bf16x8 __attribute__((ext_vector_type(8)));
typedef float f32x4  __attribute__((ext_vector_type(4)));

__device__ __forceinline__ unsigned short f2bf(float x) {
    union { float f; unsigned u; } v; v.f = x;
    unsigned r = v.u + 0x7fff + ((v.u >> 16) & 1);
    return (unsigned short)(r >> 16);
}
__device__ __forceinline__ float bf2f(unsigned short h) {
    union { unsigned u; float f; } v; v.u = ((unsigned)h) << 16;
    return v.f;
}

// ================= bf16 MFMA GEMM: C[N,M] = sum_seg A_seg[N,K] @ (BT_seg[M,K])^T =================
// 128x128 tile, 256 threads (4 waves), each wave 64x64 via 4x4 grid of 16x16x32 MFMA.
// BT is the weight pre-transposed to [M,K] so both operands are K-major.
#define BN 128
#define BM 128
#define BK 32
#define LSTR 56   // LDS row stride in bf16 elems (112 B: 16B-aligned, 2-way-conflict-free frag reads)

__launch_bounds__(256)
__global__ void gemm_mfma(const unsigned short* __restrict__ A0, const unsigned short* __restrict__ A1,
                          const unsigned short* __restrict__ A2,
                          const unsigned short* __restrict__ B0, const unsigned short* __restrict__ B1,
                          const unsigned short* __restrict__ B2,
                          int nseg, const float* __restrict__ bias,
                          float* __restrict__ C32, unsigned short* __restrict__ C16,
                          int N, int K, int M, int relu)
{
    __shared__ unsigned short As[BN * LSTR];
    __shared__ unsigned short Bs[BM * LSTR];

    const int tid  = threadIdx.x;
    const int wave = tid >> 6;
    const int lane = tid & 63;
    const int n0 = blockIdx.y * BN;
    const int m0 = blockIdx.x * BM;
    const int wrow = (wave >> 1) * 64;
    const int wcol = (wave & 1) * 64;
    const int lm   = lane & 15;
    const int quad = lane >> 4;

    f32x4 acc[4][4];
    #pragma unroll
    for (int i = 0; i < 4; ++i)
        #pragma unroll
        for (int j = 0; j < 4; ++j)
            acc[i][j] = (f32x4)0.0f;

    const int srow = tid >> 2;          // 0..63 (two chunks cover 128 rows)
    const int scg  = (tid & 3) << 3;    // 0,8,16,24 (bf16 elems; 16B each)

    for (int seg = 0; seg < nseg; ++seg) {
        const unsigned short* Aseg = (seg == 0) ? A0 : (seg == 1) ? A1 : A2;
        const unsigned short* Bseg = (seg == 0) ? B0 : (seg == 1) ? B1 : B2;

        for (int k0 = 0; k0 < K; k0 += BK) {
            __syncthreads();
            // stage A: rows n0..n0+127, k cols k0..k0+31
            #pragma unroll
            for (int c = 0; c < 2; ++c) {
                int row = srow + c * 64;
                float4 v = make_float4(0.f, 0.f, 0.f, 0.f);
                if (n0 + row < N)
                    v = *(const float4*)(Aseg + (size_t)(n0 + row) * K + k0 + scg);
                *(float4*)&As[row * LSTR + scg] = v;
            }
            // stage B (BT[M,K]): rows m0..m0+127
            #pragma unroll
            for (int c = 0; c < 2; ++c) {
                int row = srow + c * 64;
                float4 v = make_float4(0.f, 0.f, 0.f, 0.f);
                if (m0 + row < M)
                    v = *(const float4*)(Bseg + (size_t)(m0 + row) * K + k0 + scg);
                *(float4*)&Bs[row * LSTR + scg] = v;
            }
            __syncthreads();

            bf16x8 af[4], bf[4];
            #pragma unroll
            for (int i = 0; i < 4; ++i)
                af[i] = *(const bf16x8*)&As[(wrow + i * 16 + lm) * LSTR + quad * 8];
            #pragma unroll
            for (int j = 0; j < 4; ++j)
                bf[j] = *(const bf16x8*)&Bs[(wcol + j * 16 + lm) * LSTR + quad * 8];
            #pragma unroll
            for (int i = 0; i < 4; ++i)
                #pragma unroll
                for (int j = 0; j < 4; ++j)
                    acc[i][j] = __builtin_amdgcn_mfma_f32_16x16x32_bf16(af[i], bf[j], acc[i][j], 0, 0, 0);
        }
    }

    // epilogue: C/D layout col=lane&15, row=quad*4+reg
    float bj[4];
    #pragma unroll
    for (int j = 0; j < 4; ++j) {
        int gcol = m0 + wcol + j * 16 + lm;
        bj[j] = (bias && gcol < M) ? bias[gcol] : 0.f;
    }
    #pragma unroll
    for (int i = 0; i < 4; ++i) {
        #pragma unroll
        for (int r = 0; r < 4; ++r) {
            int grow = n0 + wrow + i * 16 + quad * 4 + r;
            if (grow >= N) continue;
            #pragma unroll
            for (int j = 0; j < 4; ++j) {
                int gcol = m0 + wcol + j * 16 + lm;
                if (gcol >= M) continue;
                float v = acc[i][j][r] + bj[j];
                if (relu) v = fmaxf(v, 0.f);
                if (C32) C32[(size_t)grow * M + gcol] = v;
                if (C16) C16[(size_t)grow * M + gcol] = f2bf(v);
            }
        }
    }
}

// ---------------- conversions ----------------
__global__ void xconv_kernel(const float* __restrict__ x, unsigned short* __restrict__ o, int n4)
{
    int i = blockIdx.x * blockDim.x + threadIdx.x;
    if (i >= n4) return;
    float4 v = ((const float4*)x)[i];
    ushort4 u;
    u.x = f2bf(v.x); u.y = f2bf(v.y); u.z = f2bf(v.z); u.w = f2bf(v.w);
    ((ushort4*)o)[i] = u;
}

// transpose+convert: W[K,M] fp32 -> WT[M,K] bf16, batched over `count` matrices
__global__ void wconv_kernel(const float* __restrict__ W, unsigned short* __restrict__ WT,
                             int K, int M, int count)
{
    int idx = blockIdx.x * blockDim.x + threadIdx.x;
    int per = K * M;
    if (idx >= per * count) return;
    int b = idx / per, rem = idx - b * per;
    int k = rem / M, m = rem - k * M;
    WT[(size_t)b * per + (size_t)m * K + k] = f2bf(W[idx]);
}

// WsumT[l][m][k] = bf16(Wself[l,0,k,m] + Wself[l,1,k,m])
__global__ void wsum_kernel(const float* __restrict__ Wself, unsigned short* __restrict__ WT)
{
    int idx = blockIdx.x * blockDim.x + threadIdx.x;
    const int per = H_DIM * H_DIM;
    if (idx >= 2 * per) return;
    int l = idx / per, rem = idx - l * per;
    int k = rem / H_DIM, m = rem - k * H_DIM;
    float v = Wself[(size_t)(l * 3 + 0) * per + rem] + Wself[(size_t)(l * 3 + 1) * per + rem];
    WT[(size_t)l * per + (size_t)m * H_DIM + k] = f2bf(v);
}

__global__ void bsum_kernel(const float* __restrict__ bconv, float* __restrict__ bsum)
{
    int idx = blockIdx.x * blockDim.x + threadIdx.x;
    if (idx >= 2 * H_DIM) return;
    int l = idx >> 8, j = idx & 255;
    bsum[idx] = bconv[(l * 3 + 0) * H_DIM + j] + bconv[(l * 3 + 1) * H_DIM + j];
}

// ---------------- CSR build ----------------
__global__ void degi_kernel(const int* __restrict__ dst, int* __restrict__ deg, int E)
{
    int i = blockIdx.x * blockDim.x + threadIdx.x;
    if (i < E) atomicAdd(&deg[dst[i]], 1);
}

__device__ __forceinline__ int block_exscan256(int val, int* lds, int* total)
{
    int t = threadIdx.x;
    lds[t] = val;
    __syncthreads();
    #pragma unroll
    for (int off = 1; off < 256; off <<= 1) {
        int y = (t >= off) ? lds[t - off] : 0;
        __syncthreads();
        lds[t] += y;
        __syncthreads();
    }
    int inc = lds[t];
    *total = lds[255];
    __syncthreads();
    return inc - val;
}

__global__ void scan1_kernel(const int* __restrict__ in, int* __restrict__ out,
                             int* __restrict__ sums, int n)
{
    __shared__ int lds[256];
    int t = threadIdx.x;
    int base = blockIdx.x * 1024 + t * 4;
    int v0 = 0, v1 = 0, v2 = 0, v3 = 0;
    if (base + 3 < n) {
        int4 q = *(const int4*)(in + base);
        v0 = q.x; v1 = q.y; v2 = q.z; v3 = q.w;
    } else {
        if (base     < n) v0 = in[base];
        if (base + 1 < n) v1 = in[base + 1];
        if (base + 2 < n) v2 = in[base + 2];
    }
    int tot = v0 + v1 + v2 + v3, bt;
    int ex = block_exscan256(tot, lds, &bt);
    if (base     < n) out[base]     = ex;
    if (base + 1 < n) out[base + 1] = ex + v0;
    if (base + 2 < n) out[base + 2] = ex + v0 + v1;
    if (base + 3 < n) out[base + 3] = ex + v0 + v1 + v2;
    if (t == 0) sums[blockIdx.x] = bt;
}

__global__ void scan2_kernel(int* __restrict__ sums, int nc)
{
    __shared__ int lds[256];
    int t = threadIdx.x;
    int v = (t < nc) ? sums[t] : 0;
    int bt;
    int ex = block_exscan256(v, lds, &bt);
    if (t < nc) sums[t] = ex;
}

__global__ void scan3_kernel(int* __restrict__ cur, const int* __restrict__ sums, int n)
{
    int i = blockIdx.x * blockDim.x + threadIdx.x;
    if (i < n) cur[i] += sums[i >> 10];
}

__global__ void csr_fill_kernel(const int* __restrict__ src, const int* __restrict__ dst,
                                int* __restrict__ cur, int* __restrict__ csr, int E)
{
    int e = blockIdx.x * blockDim.x + threadIdx.x;
    if (e < E) {
        int pos = atomicAdd(&cur[dst[e]], 1);
        csr[pos] = src[e];
    }
}

// ---------------- pull-style mean aggregation (bf16 in, bf16 out) ----------------
__launch_bounds__(256)
__global__ void gather_mean_kernel(const unsigned short* __restrict__ h, const int* __restrict__ cur,
                                   const int* __restrict__ deg, const int* __restrict__ csr,
                                   unsigned short* __restrict__ agg, int N)
{
    int gid = blockIdx.x * blockDim.x + threadIdx.x;
    int d = gid >> 6;
    if (d >= N) return;
    int lane = threadIdx.x & 63;
    int dg = deg[d];
    int o  = cur[d] - dg;
    float ax = 0.f, ay = 0.f, az = 0.f, aw = 0.f;
    for (int i = 0; i < dg; ++i) {
        int s = csr[o + i];
        ushort4 v = *(const ushort4*)(h + (size_t)s * H_DIM + lane * 4);
        ax += bf2f(v.x); ay += bf2f(v.y); az += bf2f(v.z); aw += bf2f(v.w);
    }
    float r = (dg > 0) ? (1.0f / (float)dg) : 0.f;
    ushort4 u;
    u.x = f2bf(ax * r); u.y = f2bf(ay * r); u.z = f2bf(az * r); u.w = f2bf(aw * r);
    *(ushort4*)(agg + (size_t)d * H_DIM + lane * 4) = u;
}

// ---------------- fused relu + residual(bf16) + LayerNorm -> bf16 (dst may alias prev) ---------
__launch_bounds__(256)
__global__ void ln_residual_kernel(const float* __restrict__ outv, const unsigned short* __restrict__ prev,
                                   const float* __restrict__ g, const float* __restrict__ b,
                                   unsigned short* __restrict__ dst, int N)
{
    int gid = blockIdx.x * blockDim.x + threadIdx.x;
    int row = gid >> 6;
    if (row >= N) return;
    int lane = threadIdx.x & 63;
    float4 o = ((const float4*)outv)[(size_t)row * (H_DIM / 4) + lane];
    ushort4 p = *(const ushort4*)(prev + (size_t)row * H_DIM + lane * 4);
    float rx = fmaxf(o.x, 0.f) + bf2f(p.x);
    float ry = fmaxf(o.y, 0.f) + bf2f(p.y);
    float rz = fmaxf(o.z, 0.f) + bf2f(p.z);
    float rw = fmaxf(o.w, 0.f) + bf2f(p.w);
    float s = rx + ry + rz + rw;
    float q = rx * rx + ry * ry + rz * rz + rw * rw;
    #pragma unroll
    for (int off = 32; off; off >>= 1) {
        s += __shfl_xor(s, off, 64);
        q += __shfl_xor(q, off, 64);
    }
    float mean = s * (1.0f / H_DIM);
    float var  = q * (1.0f / H_DIM) - mean * mean;
    float inv  = rsqrtf(var + EPS_LN);
    float4 gv = ((const float4*)g)[lane];
    float4 bv = ((const float4*)b)[lane];
    ushort4 u;
    u.x = f2bf((rx - mean) * inv * gv.x + bv.x);
    u.y = f2bf((ry - mean) * inv * gv.y + bv.y);
    u.z = f2bf((rz - mean) * inv * gv.z + bv.z);
    u.w = f2bf((rw - mean) * inv * gv.w + bv.w);
    *(ushort4*)(dst + (size_t)row * H_DIM + lane * 4) = u;
}

// ---------------- in-place log_softmax ----------------
__launch_bounds__(256)
__global__ void logsoftmax_kernel(float* __restrict__ x, int N, int C)
{
    int gid = blockIdx.x * blockDim.x + threadIdx.x;
    int row = gid >> 6;
    if (row >= N) return;
    int lane = threadIdx.x & 63;
    float v = (lane < C) ? x[(size_t)row * C + lane] : -3.0e38f;
    float m = v;
    #pragma unroll
    for (int off = 32; off; off >>= 1) m = fmaxf(m, __shfl_xor(m, off, 64));
    float e = (lane < C) ? __expf(v - m) : 0.f;
    float s = e;
    #pragma unroll
    for (int off = 32; off; off >>= 1) s += __shfl_xor(s, off, 64);
    float ls = logf(s);
    if (lane < C) x[(size_t)row * C + lane] = v - m - ls;
}

// ======================================================================================
extern "C" void kernel_launch(void* const* d_in, const int* in_sizes, int n_in,
                              void* d_out, int out_size, void* d_ws, size_t ws_size,
                              hipStream_t stream)
{
    const float* x_author = (const float*)d_in[0];
    const float* x_paper  = (const float*)d_in[1];
    const int* e0s = (const int*)d_in[2]; const int* e0d = (const int*)d_in[3];
    const int* e1s = (const int*)d_in[4]; const int* e1d = (const int*)d_in[5];
    const int* e2s = (const int*)d_in[6]; const int* e2d = (const int*)d_in[7];
    const float* embWa = (const float*)d_in[8];  const float* embba = (const float*)d_in[9];
    const float* embWp = (const float*)d_in[10]; const float* embbp = (const float*)d_in[11];
    const float* Wself  = (const float*)d_in[12];
    const float* Wneigh = (const float*)d_in[13];
    const float* bconv  = (const float*)d_in[14];
    const float* lnga = (const float*)d_in[15]; const float* lnba = (const float*)d_in[16];
    const float* lngp = (const float*)d_in[17]; const float* lnbp = (const float*)d_in[18];
    const float* pW1a = (const float*)d_in[19]; const float* pb1a = (const float*)d_in[20];
    const float* pW2a = (const float*)d_in[21]; const float* pb2a = (const float*)d_in[22];
    const float* pW1p = (const float*)d_in[23]; const float* pb1p = (const float*)d_in[24];
    const float* pW2p = (const float*)d_in[25];

    // ---- workspace carve (floats, then ushorts, then ints; all 16B-aligned sizes) ----
    char* wp = (char*)d_ws;
    auto carveF = [&](size_t n) { float* p = (float*)wp; wp += n * sizeof(float); return p; };
    auto carveU = [&](size_t n) { unsigned short* p = (unsigned short*)wp; wp += n * sizeof(unsigned short); return p; };
    auto carveI = [&](size_t n) { int* p = (int*)wp; wp += n * sizeof(int); return p; };

    float* OUTA32 = carveF((size_t)A_N * H_DIM);
    float* BSUM   = carveF(2 * H_DIM);

    unsigned short* HA16  = carveU((size_t)A_N * H_DIM);
    unsigned short* HP16  = carveU((size_t)P_N * H_DIM);
    unsigned short* AGG0  = carveU((size_t)P_N * H_DIM);
    unsigned short* AGG1  = carveU((size_t)P_N * H_DIM);
    unsigned short* AGGA  = carveU((size_t)A_N * H_DIM);
    unsigned short* XA16  = carveU((size_t)A_N * DIN);
    unsigned short* XP16  = carveU((size_t)P_N * DIN);
    unsigned short* WsT    = carveU(6 * H_DIM * H_DIM);
    unsigned short* WnT    = carveU(6 * H_DIM * H_DIM);
    unsigned short* WsumT  = carveU(2 * H_DIM * H_DIM);
    unsigned short* embWaT = carveU(DIN * H_DIM);
    unsigned short* embWpT = carveU(DIN * H_DIM);
    unsigned short* pW1aT  = carveU(H_DIM * H_DIM);
    unsigned short* pW2aT  = carveU(H_DIM * C_CLS);
    unsigned short* pW1pT  = carveU(H_DIM * H_DIM);
    unsigned short* pW2pT  = carveU(H_DIM * H_DIM);

    int* ideg = carveI(2 * P_N + A_N);
    int* icur = carveI(2 * P_N + A_N);
    int* icsr = carveI(3 * E_N);
    int* isum = carveI(3 * 256);

    int* deg0 = ideg; int* deg1 = deg0 + P_N; int* deg2 = deg1 + P_N;
    int* cur0 = icur; int* cur1 = cur0 + P_N; int* cur2 = cur1 + P_N;
    int* csr0 = icsr; int* csr1 = csr0 + E_N; int* csr2 = csr1 + E_N;
    int* sum0 = isum; int* sum1 = sum0 + 256; int* sum2 = sum1 + 256;

    float* oaOut = (float*)d_out;                  // A_N * C_CLS
    float* opOut = oaOut + (size_t)A_N * C_CLS;    // P_N * H_DIM
    float* OUTP32 = opOut;                         // reuse: fully overwritten by final head GEMM

    auto gemm = [&](const unsigned short* a0, const unsigned short* b0,
                    const unsigned short* a1, const unsigned short* b1,
                    const unsigned short* a2, const unsigned short* b2,
                    int nseg, const float* bias, float* c32, unsigned short* c16,
                    int N, int K, int M, int relu) {
        dim3 grid((M + BM - 1) / BM, (N + BN - 1) / BN);
        gemm_mfma<<<grid, 256, 0, stream>>>(a0, a1, a2, b0, b1, b2, nseg, bias, c32, c16, N, K, M, relu);
    };

    // ---- weight / input conversions ----
    xconv_kernel<<<((A_N * DIN / 4) + 255) / 256, 256, 0, stream>>>(x_author, XA16, A_N * DIN / 4);
    xconv_kernel<<<((P_N * DIN / 4) + 255) / 256, 256, 0, stream>>>(x_paper,  XP16, P_N * DIN / 4);
    wconv_kernel<<<(DIN * H_DIM + 255) / 256, 256, 0, stream>>>(embWa, embWaT, DIN, H_DIM, 1);
    wconv_kernel<<<(DIN * H_DIM + 255) / 256, 256, 0, stream>>>(embWp, embWpT, DIN, H_DIM, 1);
    wconv_kernel<<<(6 * H_DIM * H_DIM + 255) / 256, 256, 0, stream>>>(Wself,  WsT, H_DIM, H_DIM, 6);
    wconv_kernel<<<(6 * H_DIM * H_DIM + 255) / 256, 256, 0, stream>>>(Wneigh, WnT, H_DIM, H_DIM, 6);
    wsum_kernel<<<(2 * H_DIM * H_DIM + 255) / 256, 256, 0, stream>>>(Wself, WsumT);
    bsum_kernel<<<2, 256, 0, stream>>>(bconv, BSUM);
    wconv_kernel<<<(H_DIM * H_DIM + 255) / 256, 256, 0, stream>>>(pW1a, pW1aT, H_DIM, H_DIM, 1);
    wconv_kernel<<<(H_DIM * C_CLS + 255) / 256, 256, 0, stream>>>(pW2a, pW2aT, H_DIM, C_CLS, 1);
    wconv_kernel<<<(H_DIM * H_DIM + 255) / 256, 256, 0, stream>>>(pW1p, pW1pT, H_DIM, H_DIM, 1);
    wconv_kernel<<<(H_DIM * H_DIM + 255) / 256, 256, 0, stream>>>(pW2p, pW2pT, H_DIM, H_DIM, 1);

    // ---- CSR build ----
    hipMemsetAsync(ideg, 0, (size_t)(2 * P_N + A_N) * sizeof(int), stream);
    const int eB = (E_N + 255) / 256;
    degi_kernel<<<eB, 256, 0, stream>>>(e0d, deg0, E_N);
    degi_kernel<<<eB, 256, 0, stream>>>(e1d, deg1, E_N);
    degi_kernel<<<eB, 256, 0, stream>>>(e2d, deg2, E_N);

    auto build_scan = [&](int* deg, int* cur, int* sums, int n) {
        int nc = (n + 1023) / 1024;
        scan1_kernel<<<nc, 256, 0, stream>>>(deg, cur, sums, n);
        scan2_kernel<<<1, 256, 0, stream>>>(sums, nc);
        scan3_kernel<<<(n + 255) / 256, 256, 0, stream>>>(cur, sums, n);
    };
    build_scan(deg0, cur0, sum0, P_N);
    build_scan(deg1, cur1, sum1, P_N);
    build_scan(deg2, cur2, sum2, A_N);

    csr_fill_kernel<<<eB, 256, 0, stream>>>(e0s, e0d, cur0, csr0, E_N);
    csr_fill_kernel<<<eB, 256, 0, stream>>>(e1s, e1d, cur1, csr1, E_N);
    csr_fill_kernel<<<eB, 256, 0, stream>>>(e2s, e2d, cur2, csr2, E_N);

    // ---- input embeddings (bf16 out) ----
    gemm(XA16, embWaT, 0, 0, 0, 0, 1, embba, nullptr, HA16, A_N, DIN, H_DIM, 0);
    gemm(XP16, embWpT, 0, 0, 0, 0, 1, embbp, nullptr, HP16, P_N, DIN, H_DIM, 0);

    const int gBlkP = (P_N * 64 + 255) / 256;
    const int gBlkA = (A_N * 64 + 255) / 256;
    const size_t W2 = (size_t)H_DIM * H_DIM;

    for (int l = 0; l < 2; ++l) {
        // aggregations (read pre-update H)
        gather_mean_kernel<<<gBlkP, 256, 0, stream>>>(HA16, cur0, deg0, csr0, AGG0, P_N);
        gather_mean_kernel<<<gBlkP, 256, 0, stream>>>(HP16, cur1, deg1, csr1, AGG1, P_N);
        gather_mean_kernel<<<gBlkA, 256, 0, stream>>>(HP16, cur2, deg2, csr2, AGGA, A_N);

        // paper: out_p = hp@(Ws0+Ws1) + agg0@Wn0 + agg1@Wn1 + (b0+b1)   [3-segment fused]
        gemm(HP16, WsumT + (size_t)l * W2,
             AGG0, WnT + (size_t)(l * 3 + 0) * W2,
             AGG1, WnT + (size_t)(l * 3 + 1) * W2,
             3, BSUM + l * H_DIM, OUTP32, nullptr, P_N, H_DIM, H_DIM, 0);

        // author: out_a = ha@Ws2 + aggA@Wn2 + b2   [2-segment fused]
        gemm(HA16, WsT + (size_t)(l * 3 + 2) * W2,
             AGGA, WnT + (size_t)(l * 3 + 2) * W2,
             0, 0,
             2, bconv + (size_t)(l * 3 + 2) * H_DIM, OUTA32, nullptr, A_N, H_DIM, H_DIM, 0);

        // fused relu + residual + LN (in place into HA16 / HP16)
        ln_residual_kernel<<<gBlkA, 256, 0, stream>>>(OUTA32, HA16, lnga, lnba, HA16, A_N);
        ln_residual_kernel<<<gBlkP, 256, 0, stream>>>(OUTP32, HP16, lngp, lnbp, HP16, P_N);
    }

    // ---- output heads ----
    unsigned short* TMPA16 = AGGA;   // free after layers
    unsigned short* TMPP16 = AGG0;
    gemm(HA16, pW1aT, 0, 0, 0, 0, 1, pb1a, nullptr, TMPA16, A_N, H_DIM, H_DIM, 1);
    gemm(TMPA16, pW2aT, 0, 0, 0, 0, 1, pb2a, oaOut, nullptr, A_N, H_DIM, C_CLS, 0);
    logsoftmax_kernel<<<gBlkA, 256, 0, stream>>>(oaOut, A_N, C_CLS);

    gemm(HP16, pW1pT, 0, 0, 0, 0, 1, pb1p, nullptr, TMPP16, P_N, H_DIM, H_DIM, 1);
    gemm(TMPP16, pW2pT, 0, 0, 0, 0, 1, nullptr, opOut, nullptr, P_N, H_DIM, H_DIM, 0);
}

// Round 4
// 1091.509 us; speedup vs baseline: 8.4263x; 1.3431x over previous
//
#include <hip/hip_runtime.h>

#define A_N   50000
#define P_N   100000
#define DIN   128
#define H_DIM 256
#define C_CLS 40
#define E_N   300000
#define EPS_LN 1e-5f

typedef short bf16x8 __attribute__((ext_vector_type(8)));
typedef float f32x4  __attribute__((ext_vector_type(4)));
typedef unsigned short u16;

__device__ __forceinline__ u16 f2bf(float x) {
    union { float f; unsigned u; } v; v.f = x;
    unsigned r = v.u + 0x7fff + ((v.u >> 16) & 1);
    return (u16)(r >> 16);
}
__device__ __forceinline__ float bf2f(u16 h) {
    union { unsigned u; float f; } v; v.u = ((unsigned)h) << 16;
    return v.f;
}

// async global->LDS, 16 B per lane; lds base must be wave-uniform (HW scatters lane*16)
__device__ __forceinline__ void gl2lds16(const u16* g, u16* ldsbase) {
    __builtin_amdgcn_global_load_lds(
        (const __attribute__((address_space(1))) unsigned int*)g,
        (__attribute__((address_space(3))) unsigned int*)ldsbase, 16, 0, 0);
}

// ================= general bf16 MFMA GEMM: C[N,M] = sum_seg A_seg[N,K] @ (BT_seg[M,K])^T ======
// 128x128 tile, BK=32, 256 threads (4 waves), wave = 64x64 via 4x4 of 16x16x32 MFMA.
// LDS [row][32] unpadded (global_load_lds layout); frag b128 reads are bank-balanced.
#define GBN 128
#define GBM 128

__launch_bounds__(256)
__global__ void gemm_mfma2(const u16* __restrict__ A0, const u16* __restrict__ A1,
                           const u16* __restrict__ A2,
                           const u16* __restrict__ B0, const u16* __restrict__ B1,
                           const u16* __restrict__ B2,
                           int nseg, const float* __restrict__ bias,
                           float* __restrict__ C32, u16* __restrict__ C16,
                           int N, int K, int M, int relu)
{
    __shared__ u16 As[GBN * 32];   // 8 KB
    __shared__ u16 Bs[GBM * 32];   // 8 KB

    const int tid  = threadIdx.x;
    const int wave = tid >> 6;
    const int lane = tid & 63;
    const int n0 = blockIdx.y * GBN;
    const int m0 = blockIdx.x * GBM;
    const int wrow = (wave >> 1) * 64;
    const int wcol = (wave & 1) * 64;
    const int lm   = lane & 15;
    const int quad = lane >> 4;
    const int rg = lane >> 2;      // staging: 4 lanes/row (64 B rows), 16 rows/instr
    const int ch = lane & 3;       // 16B chunk within row

    f32x4 acc[4][4];
    #pragma unroll
    for (int i = 0; i < 4; ++i)
        #pragma unroll
        for (int j = 0; j < 4; ++j)
            acc[i][j] = (f32x4)0.0f;

    for (int seg = 0; seg < nseg; ++seg) {
        const u16* Aseg = (seg == 0) ? A0 : (seg == 1) ? A1 : A2;
        const u16* Bseg = (seg == 0) ? B0 : (seg == 1) ? B1 : B2;

        for (int k0 = 0; k0 < K; k0 += 32) {
            __syncthreads();   // previous tile fully consumed before overwrite
            #pragma unroll
            for (int i = 0; i < 2; ++i) {
                int lr = wave * 32 + i * 16;
                int grow = n0 + lr + rg; if (grow > N - 1) grow = N - 1;
                gl2lds16(Aseg + (size_t)grow * K + k0 + ch * 8, &As[lr * 32]);
            }
            #pragma unroll
            for (int i = 0; i < 2; ++i) {
                int lr = wave * 32 + i * 16;
                int brow = m0 + lr + rg; if (brow > M - 1) brow = M - 1;
                gl2lds16(Bseg + (size_t)brow * K + k0 + ch * 8, &Bs[lr * 32]);
            }
            __syncthreads();   // vmcnt drain + barrier

            bf16x8 af[4], bfr[4];
            #pragma unroll
            for (int i = 0; i < 4; ++i)
                af[i] = *(const bf16x8*)&As[(wrow + i * 16 + lm) * 32 + quad * 8];
            #pragma unroll
            for (int j = 0; j < 4; ++j)
                bfr[j] = *(const bf16x8*)&Bs[(wcol + j * 16 + lm) * 32 + quad * 8];
            #pragma unroll
            for (int i = 0; i < 4; ++i)
                #pragma unroll
                for (int j = 0; j < 4; ++j)
                    acc[i][j] = __builtin_amdgcn_mfma_f32_16x16x32_bf16(af[i], bfr[j], acc[i][j], 0, 0, 0);
        }
    }

    // epilogue: C/D layout col=lane&15, row=quad*4+reg
    float bj[4];
    #pragma unroll
    for (int j = 0; j < 4; ++j) {
        int gcol = m0 + wcol + j * 16 + lm;
        bj[j] = (bias && gcol < M) ? bias[gcol] : 0.f;
    }
    #pragma unroll
    for (int i = 0; i < 4; ++i) {
        #pragma unroll
        for (int r = 0; r < 4; ++r) {
            int grow = n0 + wrow + i * 16 + quad * 4 + r;
            if (grow >= N) continue;
            #pragma unroll
            for (int j = 0; j < 4; ++j) {
                int gcol = m0 + wcol + j * 16 + lm;
                if (gcol >= M) continue;
                float v = acc[i][j][r] + bj[j];
                if (relu) v = fmaxf(v, 0.f);
                if (C32) C32[(size_t)grow * M + gcol] = v;
                if (C16) C16[(size_t)grow * M + gcol] = f2bf(v);
            }
        }
    }
}

// ========== fused layer GEMM + relu + residual + LayerNorm, in-place on H (bf16) ==========
// BN=64 rows/block, BM=256 = full output row. wave w: rows w*16..w*16+15, all 256 cols.
// K = 256 per segment. Safe in-place: block reads only its own A rows, writes after k-loop.
__launch_bounds__(256)
__global__ void gemm_ln(const u16* __restrict__ A0, const u16* __restrict__ A1,
                        const u16* __restrict__ A2,
                        const u16* __restrict__ B0, const u16* __restrict__ B1,
                        const u16* __restrict__ B2,
                        int nseg, const float* __restrict__ bias,
                        const float* __restrict__ lng, const float* __restrict__ lnb,
                        u16* __restrict__ H, int N)
{
    __shared__ u16 As[64 * 32];    // 4 KB
    __shared__ u16 Bs[256 * 32];   // 16 KB

    const int tid  = threadIdx.x;
    const int wave = tid >> 6;
    const int lane = tid & 63;
    const int n0 = blockIdx.x * 64;
    const int lm   = lane & 15;
    const int quad = lane >> 4;
    const int rg = lane >> 2;
    const int ch = lane & 3;

    f32x4 acc[16];
    #pragma unroll
    for (int j = 0; j < 16; ++j) acc[j] = (f32x4)0.0f;

    for (int seg = 0; seg < nseg; ++seg) {
        const u16* Aseg = (seg == 0) ? A0 : (seg == 1) ? A1 : A2;
        const u16* Bseg = (seg == 0) ? B0 : (seg == 1) ? B1 : B2;

        for (int k0 = 0; k0 < H_DIM; k0 += 32) {
            __syncthreads();
            {   // A: 64 rows, wave stages its own 16
                int lr = wave * 16;
                int grow = n0 + lr + rg; if (grow > N - 1) grow = N - 1;
                gl2lds16(Aseg + (size_t)grow * H_DIM + k0 + ch * 8, &As[lr * 32]);
            }
            #pragma unroll
            for (int i = 0; i < 4; ++i) {   // B: 256 rows, wave stages 64
                int lr = wave * 64 + i * 16;
                gl2lds16(Bseg + (size_t)(lr + rg) * H_DIM + k0 + ch * 8, &Bs[lr * 32]);
            }
            __syncthreads();

            bf16x8 af = *(const bf16x8*)&As[(wave * 16 + lm) * 32 + quad * 8];
            #pragma unroll
            for (int j = 0; j < 16; ++j) {
                bf16x8 bfr = *(const bf16x8*)&Bs[(j * 16 + lm) * 32 + quad * 8];
                acc[j] = __builtin_amdgcn_mfma_f32_16x16x32_bf16(af, bfr, acc[j], 0, 0, 0);
            }
        }
    }

    // epilogue: per accumulator row: relu + bias, + residual H, LN over 256 cols, write bf16
    #pragma unroll
    for (int r = 0; r < 4; ++r) {
        int grow = n0 + wave * 16 + quad * 4 + r;   // uniform across the 16 lm lanes
        if (grow >= N) continue;
        float v[16];
        float ps = 0.f, pq = 0.f;
        #pragma unroll
        for (int j = 0; j < 16; ++j) {
            int col = j * 16 + lm;
            float x = fmaxf(acc[j][r] + bias[col], 0.f);
            x += bf2f(H[(size_t)grow * H_DIM + col]);
            v[j] = x; ps += x; pq += x * x;
        }
        #pragma unroll
        for (int off = 1; off < 16; off <<= 1) {
            ps += __shfl_xor(ps, off, 64);
            pq += __shfl_xor(pq, off, 64);
        }
        float mean = ps * (1.0f / H_DIM);
        float var  = pq * (1.0f / H_DIM) - mean * mean;
        float inv  = rsqrtf(var + EPS_LN);
        #pragma unroll
        for (int j = 0; j < 16; ++j) {
            int col = j * 16 + lm;
            H[(size_t)grow * H_DIM + col] = f2bf((v[j] - mean) * inv * lng[col] + lnb[col]);
        }
    }
}

// ---------------- conversions ----------------
__global__ void xconv_kernel(const float* __restrict__ x, u16* __restrict__ o, int n4)
{
    int i = blockIdx.x * blockDim.x + threadIdx.x;
    if (i >= n4) return;
    float4 v = ((const float4*)x)[i];
    ushort4 u;
    u.x = f2bf(v.x); u.y = f2bf(v.y); u.z = f2bf(v.z); u.w = f2bf(v.w);
    ((ushort4*)o)[i] = u;
}

__global__ void wconv_kernel(const float* __restrict__ W, u16* __restrict__ WT,
                             int K, int M, int count)
{
    int idx = blockIdx.x * blockDim.x + threadIdx.x;
    int per = K * M;
    if (idx >= per * count) return;
    int b = idx / per, rem = idx - b * per;
    int k = rem / M, m = rem - k * M;
    WT[(size_t)b * per + (size_t)m * K + k] = f2bf(W[idx]);
}

__global__ void wsum_kernel(const float* __restrict__ Wself, u16* __restrict__ WT)
{
    int idx = blockIdx.x * blockDim.x + threadIdx.x;
    const int per = H_DIM * H_DIM;
    if (idx >= 2 * per) return;
    int l = idx / per, rem = idx - l * per;
    int k = rem / H_DIM, m = rem - k * H_DIM;
    float v = Wself[(size_t)(l * 3 + 0) * per + rem] + Wself[(size_t)(l * 3 + 1) * per + rem];
    WT[(size_t)l * per + (size_t)m * H_DIM + k] = f2bf(v);
}

__global__ void bsum_kernel(const float* __restrict__ bconv, float* __restrict__ bsum)
{
    int idx = blockIdx.x * blockDim.x + threadIdx.x;
    if (idx >= 2 * H_DIM) return;
    int l = idx >> 8, j = idx & 255;
    bsum[idx] = bconv[(l * 3 + 0) * H_DIM + j] + bconv[(l * 3 + 1) * H_DIM + j];
}

// ---------------- CSR build ----------------
__global__ void degi_kernel(const int* __restrict__ dst, int* __restrict__ deg, int E)
{
    int i = blockIdx.x * blockDim.x + threadIdx.x;
    if (i < E) atomicAdd(&deg[dst[i]], 1);
}

__device__ __forceinline__ int block_exscan256(int val, int* lds, int* total)
{
    int t = threadIdx.x;
    lds[t] = val;
    __syncthreads();
    #pragma unroll
    for (int off = 1; off < 256; off <<= 1) {
        int y = (t >= off) ? lds[t - off] : 0;
        __syncthreads();
        lds[t] += y;
        __syncthreads();
    }
    int inc = lds[t];
    *total = lds[255];
    __syncthreads();
    return inc - val;
}

__global__ void scan1_kernel(const int* __restrict__ in, int* __restrict__ out,
                             int* __restrict__ sums, int n)
{
    __shared__ int lds[256];
    int t = threadIdx.x;
    int base = blockIdx.x * 1024 + t * 4;
    int v0 = 0, v1 = 0, v2 = 0, v3 = 0;
    if (base + 3 < n) {
        int4 q = *(const int4*)(in + base);
        v0 = q.x; v1 = q.y; v2 = q.z; v3 = q.w;
    } else {
        if (base     < n) v0 = in[base];
        if (base + 1 < n) v1 = in[base + 1];
        if (base + 2 < n) v2 = in[base + 2];
    }
    int tot = v0 + v1 + v2 + v3, bt;
    int ex = block_exscan256(tot, lds, &bt);
    if (base     < n) out[base]     = ex;
    if (base + 1 < n) out[base + 1] = ex + v0;
    if (base + 2 < n) out[base + 2] = ex + v0 + v1;
    if (base + 3 < n) out[base + 3] = ex + v0 + v1 + v2;
    if (t == 0) sums[blockIdx.x] = bt;
}

__global__ void scan2_kernel(int* __restrict__ sums, int nc)
{
    __shared__ int lds[256];
    int t = threadIdx.x;
    int v = (t < nc) ? sums[t] : 0;
    int bt;
    int ex = block_exscan256(v, lds, &bt);
    if (t < nc) sums[t] = ex;
}

__global__ void scan3_kernel(int* __restrict__ cur, const int* __restrict__ sums, int n)
{
    int i = blockIdx.x * blockDim.x + threadIdx.x;
    if (i < n) cur[i] += sums[i >> 10];
}

__global__ void csr_fill_kernel(const int* __restrict__ src, const int* __restrict__ dst,
                                int* __restrict__ cur, int* __restrict__ csr, int E)
{
    int e = blockIdx.x * blockDim.x + threadIdx.x;
    if (e < E) {
        int pos = atomicAdd(&cur[dst[e]], 1);
        csr[pos] = src[e];
    }
}

// ---------------- pull-style mean aggregation: 2 dst rows per wave, 16 B/lane ----------------
typedef unsigned short u16x8 __attribute__((ext_vector_type(8)));

__launch_bounds__(256)
__global__ void gather_mean_kernel(const u16* __restrict__ h, const int* __restrict__ cur,
                                   const int* __restrict__ deg, const int* __restrict__ csr,
                                   u16* __restrict__ agg, int N)
{
    int gid = blockIdx.x * blockDim.x + threadIdx.x;
    int d = gid >> 5;
    if (d >= N) return;
    int l = gid & 31;               // 32 chunks of 8 bf16 per 256-wide row
    int dg = deg[d];
    int o  = cur[d] - dg;
    float a[8] = {};
    for (int i = 0; i < dg; ++i) {
        int s = csr[o + i];
        u16x8 v = *(const u16x8*)(h + (size_t)s * H_DIM + l * 8);
        #pragma unroll
        for (int t = 0; t < 8; ++t) a[t] += bf2f(v[t]);
    }
    float r = (dg > 0) ? (1.0f / (float)dg) : 0.f;
    u16x8 u;
    #pragma unroll
    for (int t = 0; t < 8; ++t) u[t] = f2bf(a[t] * r);
    *(u16x8*)(agg + (size_t)d * H_DIM + l * 8) = u;
}

// ---------------- in-place log_softmax ----------------
__launch_bounds__(256)
__global__ void logsoftmax_kernel(float* __restrict__ x, int N, int C)
{
    int gid = blockIdx.x * blockDim.x + threadIdx.x;
    int row = gid >> 6;
    if (row >= N) return;
    int lane = threadIdx.x & 63;
    float v = (lane < C) ? x[(size_t)row * C + lane] : -3.0e38f;
    float m = v;
    #pragma unroll
    for (int off = 32; off; off >>= 1) m = fmaxf(m, __shfl_xor(m, off, 64));
    float e = (lane < C) ? __expf(v - m) : 0.f;
    float s = e;
    #pragma unroll
    for (int off = 32; off; off >>= 1) s += __shfl_xor(s, off, 64);
    float ls = logf(s);
    if (lane < C) x[(size_t)row * C + lane] = v - m - ls;
}

// ======================================================================================
extern "C" void kernel_launch(void* const* d_in, const int* in_sizes, int n_in,
                              void* d_out, int out_size, void* d_ws, size_t ws_size,
                              hipStream_t stream)
{
    const float* x_author = (const float*)d_in[0];
    const float* x_paper  = (const float*)d_in[1];
    const int* e0s = (const int*)d_in[2]; const int* e0d = (const int*)d_in[3];
    const int* e1s = (const int*)d_in[4]; const int* e1d = (const int*)d_in[5];
    const int* e2s = (const int*)d_in[6]; const int* e2d = (const int*)d_in[7];
    const float* embWa = (const float*)d_in[8];  const float* embba = (const float*)d_in[9];
    const float* embWp = (const float*)d_in[10]; const float* embbp = (const float*)d_in[11];
    const float* Wself  = (const float*)d_in[12];
    const float* Wneigh = (const float*)d_in[13];
    const float* bconv  = (const float*)d_in[14];
    const float* lnga = (const float*)d_in[15]; const float* lnba = (const float*)d_in[16];
    const float* lngp = (const float*)d_in[17]; const float* lnbp = (const float*)d_in[18];
    const float* pW1a = (const float*)d_in[19]; const float* pb1a = (const float*)d_in[20];
    const float* pW2a = (const float*)d_in[21]; const float* pb2a = (const float*)d_in[22];
    const float* pW1p = (const float*)d_in[23]; const float* pb1p = (const float*)d_in[24];
    const float* pW2p = (const float*)d_in[25];

    // ---- workspace carve ----
    char* wp = (char*)d_ws;
    auto carveF = [&](size_t n) { float* p = (float*)wp; wp += n * sizeof(float); return p; };
    auto carveU = [&](size_t n) { u16* p = (u16*)wp; wp += n * sizeof(u16); return p; };
    auto carveI = [&](size_t n) { int* p = (int*)wp; wp += n * sizeof(int); return p; };

    float* BSUM = carveF(2 * H_DIM);

    u16* HA16  = carveU((size_t)A_N * H_DIM);
    u16* HP16  = carveU((size_t)P_N * H_DIM);
    u16* AGG0  = carveU((size_t)P_N * H_DIM);
    u16* AGG1  = carveU((size_t)P_N * H_DIM);
    u16* AGGA  = carveU((size_t)A_N * H_DIM);
    u16* XA16  = carveU((size_t)A_N * DIN);
    u16* XP16  = carveU((size_t)P_N * DIN);
    u16* WsT    = carveU(6 * H_DIM * H_DIM);
    u16* WnT    = carveU(6 * H_DIM * H_DIM);
    u16* WsumT  = carveU(2 * H_DIM * H_DIM);
    u16* embWaT = carveU(DIN * H_DIM);
    u16* embWpT = carveU(DIN * H_DIM);
    u16* pW1aT  = carveU(H_DIM * H_DIM);
    u16* pW2aT  = carveU(H_DIM * C_CLS);
    u16* pW1pT  = carveU(H_DIM * H_DIM);
    u16* pW2pT  = carveU(H_DIM * H_DIM);

    int* ideg = carveI(2 * P_N + A_N);
    int* icur = carveI(2 * P_N + A_N);
    int* icsr = carveI(3 * E_N);
    int* isum = carveI(3 * 256);

    int* deg0 = ideg; int* deg1 = deg0 + P_N; int* deg2 = deg1 + P_N;
    int* cur0 = icur; int* cur1 = cur0 + P_N; int* cur2 = cur1 + P_N;
    int* csr0 = icsr; int* csr1 = csr0 + E_N; int* csr2 = csr1 + E_N;
    int* sum0 = isum; int* sum1 = sum0 + 256; int* sum2 = sum1 + 256;

    float* oaOut = (float*)d_out;                  // A_N * C_CLS
    float* opOut = oaOut + (size_t)A_N * C_CLS;    // P_N * H_DIM

    auto gemm = [&](const u16* a0, const u16* b0, const u16* a1, const u16* b1,
                    const u16* a2, const u16* b2, int nseg, const float* bias,
                    float* c32, u16* c16, int N, int K, int M, int relu) {
        dim3 grid((M + GBM - 1) / GBM, (N + GBN - 1) / GBN);
        gemm_mfma2<<<grid, 256, 0, stream>>>(a0, a1, a2, b0, b1, b2, nseg, bias, c32, c16, N, K, M, relu);
    };

    // ---- weight / input conversions ----
    xconv_kernel<<<((A_N * DIN / 4) + 255) / 256, 256, 0, stream>>>(x_author, XA16, A_N * DIN / 4);
    xconv_kernel<<<((P_N * DIN / 4) + 255) / 256, 256, 0, stream>>>(x_paper,  XP16, P_N * DIN / 4);
    wconv_kernel<<<(DIN * H_DIM + 255) / 256, 256, 0, stream>>>(embWa, embWaT, DIN, H_DIM, 1);
    wconv_kernel<<<(DIN * H_DIM + 255) / 256, 256, 0, stream>>>(embWp, embWpT, DIN, H_DIM, 1);
    wconv_kernel<<<(6 * H_DIM * H_DIM + 255) / 256, 256, 0, stream>>>(Wself,  WsT, H_DIM, H_DIM, 6);
    wconv_kernel<<<(6 * H_DIM * H_DIM + 255) / 256, 256, 0, stream>>>(Wneigh, WnT, H_DIM, H_DIM, 6);
    wsum_kernel<<<(2 * H_DIM * H_DIM + 255) / 256, 256, 0, stream>>>(Wself, WsumT);
    bsum_kernel<<<2, 256, 0, stream>>>(bconv, BSUM);
    wconv_kernel<<<(H_DIM * H_DIM + 255) / 256, 256, 0, stream>>>(pW1a, pW1aT, H_DIM, H_DIM, 1);
    wconv_kernel<<<(H_DIM * C_CLS + 255) / 256, 256, 0, stream>>>(pW2a, pW2aT, H_DIM, C_CLS, 1);
    wconv_kernel<<<(H_DIM * H_DIM + 255) / 256, 256, 0, stream>>>(pW1p, pW1pT, H_DIM, H_DIM, 1);
    wconv_kernel<<<(H_DIM * H_DIM + 255) / 256, 256, 0, stream>>>(pW2p, pW2pT, H_DIM, H_DIM, 1);

    // ---- CSR build ----
    hipMemsetAsync(ideg, 0, (size_t)(2 * P_N + A_N) * sizeof(int), stream);
    const int eB = (E_N + 255) / 256;
    degi_kernel<<<eB, 256, 0, stream>>>(e0d, deg0, E_N);
    degi_kernel<<<eB, 256, 0, stream>>>(e1d, deg1, E_N);
    degi_kernel<<<eB, 256, 0, stream>>>(e2d, deg2, E_N);

    auto build_scan = [&](int* deg, int* cur, int* sums, int n) {
        int nc = (n + 1023) / 1024;
        scan1_kernel<<<nc, 256, 0, stream>>>(deg, cur, sums, n);
        scan2_kernel<<<1, 256, 0, stream>>>(sums, nc);
        scan3_kernel<<<(n + 255) / 256, 256, 0, stream>>>(cur, sums, n);
    };
    build_scan(deg0, cur0, sum0, P_N);
    build_scan(deg1, cur1, sum1, P_N);
    build_scan(deg2, cur2, sum2, A_N);

    csr_fill_kernel<<<eB, 256, 0, stream>>>(e0s, e0d, cur0, csr0, E_N);
    csr_fill_kernel<<<eB, 256, 0, stream>>>(e1s, e1d, cur1, csr1, E_N);
    csr_fill_kernel<<<eB, 256, 0, stream>>>(e2s, e2d, cur2, csr2, E_N);

    // ---- input embeddings (bf16 out) ----
    gemm(XA16, embWaT, 0, 0, 0, 0, 1, embba, nullptr, HA16, A_N, DIN, H_DIM, 0);
    gemm(XP16, embWpT, 0, 0, 0, 0, 1, embbp, nullptr, HP16, P_N, DIN, H_DIM, 0);

    const int gaBlkP = (P_N * 32 + 255) / 256;
    const int gaBlkA = (A_N * 32 + 255) / 256;
    const size_t W2 = (size_t)H_DIM * H_DIM;

    for (int l = 0; l < 2; ++l) {
        // aggregations (read pre-update H)
        gather_mean_kernel<<<gaBlkP, 256, 0, stream>>>(HA16, cur0, deg0, csr0, AGG0, P_N);
        gather_mean_kernel<<<gaBlkP, 256, 0, stream>>>(HP16, cur1, deg1, csr1, AGG1, P_N);
        gather_mean_kernel<<<gaBlkA, 256, 0, stream>>>(HP16, cur2, deg2, csr2, AGGA, A_N);

        // paper: hp@(Ws0+Ws1) + agg0@Wn0 + agg1@Wn1 + (b0+b1), then relu+residual+LN in-place
        gemm_ln<<<(P_N + 63) / 64, 256, 0, stream>>>(
            HP16, AGG0, AGG1,
            WsumT + (size_t)l * W2, WnT + (size_t)(l * 3 + 0) * W2, WnT + (size_t)(l * 3 + 1) * W2,
            3, BSUM + l * H_DIM, lngp, lnbp, HP16, P_N);

        // author: ha@Ws2 + aggA@Wn2 + b2, then relu+residual+LN in-place
        gemm_ln<<<(A_N + 63) / 64, 256, 0, stream>>>(
            HA16, AGGA, (const u16*)nullptr,
            WsT + (size_t)(l * 3 + 2) * W2, WnT + (size_t)(l * 3 + 2) * W2, (const u16*)nullptr,
            2, bconv + (size_t)(l * 3 + 2) * H_DIM, lnga, lnba, HA16, A_N);
    }

    // ---- output heads ----
    u16* TMPA16 = AGGA;   // free after layers
    u16* TMPP16 = AGG0;
    gemm(HA16, pW1aT, 0, 0, 0, 0, 1, pb1a, nullptr, TMPA16, A_N, H_DIM, H_DIM, 1);
    gemm(TMPA16, pW2aT, 0, 0, 0, 0, 1, pb2a, oaOut, nullptr, A_N, H_DIM, C_CLS, 0);
    logsoftmax_kernel<<<(A_N * 64 + 255) / 256, 256, 0, stream>>>(oaOut, A_N, C_CLS);

    gemm(HP16, pW1pT, 0, 0, 0, 0, 1, pb1p, nullptr, TMPP16, P_N, H_DIM, H_DIM, 1);
    gemm(TMPP16, pW2pT, 0, 0, 0, 0, 1, nullptr, opOut, nullptr, P_N, H_DIM, H_DIM, 0);
}